// Round 3
// baseline (214.234 us; speedup 1.0000x reference)
//
#include <hip/hip_runtime.h>

// Problem constants
#define NTOT 512   // N
#define NH   448   // N - K
#define KK   64    // K
#define NL   30688 // strictly-lower entries in last K rows
#define DD   16    // domains
#define LISTCAP 1024
#define SLICES 16  // kernel-B blocks per domain
#define MAXG 4     // samples per block-iteration in kernel B

// ws layout (bytes):
//   [0,64)                     counts[16] (int)
//   [1024, 1024+64K)           lists[16][1024] (int)
//   [66560, 66560+2MB)         W: [dom][j>>2][r][j&3] f32 (solved tail operator, transposed+quad-packed)
#define WS_LISTS_OFF 1024
#define WS_W_OFF     66560

// W_d = (I-U_d)^{-1} [T_d | diag(s_d)]  (64 x 512). Then z_tail[b] = W_{d_b} @ eps[b].
// Row r of rhs: [ T[r][0:448] | s_r at col 448+r ].  Forward substitution:
//   W[r] = rhs[r] + sum_{m<r} U[r][m] * W[m]
// T row r at L_emb[dom] + 448r + r(r-1)/2; U[r][m] at +448+m.  Domain 0: W = [0 | I].

// ---------- Kernel A: scan buckets + solve W per domain + head copy ----------
__global__ __launch_bounds__(256)
void fvae_prep(const float* __restrict__ eps, const int* __restrict__ dom_idx,
               const float* __restrict__ L_emb, const float* __restrict__ S_emb,
               const float* __restrict__ bias_sh, float* __restrict__ out,
               float* __restrict__ ws, int B)
{
    __shared__ float T_s[KK][256];
    __shared__ float U_s[(KK * (KK - 1)) / 2];   // packed strictly-lower
    const int bid = blockIdx.x;
    const int tid = threadIdx.x;

    if (bid < DD) {
        // ---- bucket scan: block d enumerates samples with dom_idx == d (wave 0)
        if (tid < 64) {
            const int dom = bid;
            int* counts = (int*)ws;
            int* lists  = (int*)((char*)ws + WS_LISTS_OFF) + dom * LISTCAP;
            int base = 0;
            const int nt = B >> 6;
            #pragma unroll 4
            for (int t = 0; t < nt; ++t) {
                const int pos = t * 64 + tid;
                const int dm  = dom_idx[pos];
                const unsigned long long m = __ballot(dm == dom);
                if (dm == dom) {
                    const int rank = base + __popcll(m & ((1ull << tid) - 1ull));
                    lists[rank] = pos;
                }
                base += __popcll(m);
            }
            if (tid == 0) counts[dom] = base;
        }
        return;
    }

    if (bid < DD + 32) {
        // ---- solve W: (domain, column-chunk of 256); thread = one column
        const int sb  = bid - DD;
        const int dom = sb >> 1;
        const int c   = (sb & 1) * 256 + tid;   // global column 0..511
        const int k   = c - NH;                 // diag index if >= 0
        float* __restrict__ W = (float*)((char*)ws + WS_W_OFF) + dom * (NTOT * KK);

        if (dom == 0) {   // L=0, S=I  ->  W = [0 | I]
            #pragma unroll
            for (int r = 0; r < KK; ++r)
                W[(c >> 2) * 256 + r * 4 + (c & 3)] = (k == r) ? 1.f : 0.f;
            return;
        }
        const float* __restrict__ Ld = L_emb + (size_t)dom * NL;
        for (int r0 = (tid >> 6); r0 < KK; r0 += 4) {      // stage packed U
            const int l = tid & 63;
            if (l < r0)
                U_s[(r0 * (r0 - 1)) / 2 + l] = Ld[r0 * NH + (r0 * (r0 - 1)) / 2 + NH + l];
        }
        #pragma unroll 8
        for (int r = 0; r < KK; ++r)                        // stage T chunk (coalesced)
            if (c < NH) T_s[r][tid] = Ld[r * NH + (r * (r - 1)) / 2 + c];
        __syncthreads();

        const float s_own = (k >= 0) ? S_emb[dom * KK + k] : 0.f;
        float w[KK];                                        // fully static-indexed (rule #20)
        #pragma unroll
        for (int r = 0; r < KK; ++r) {
            const float rhs = (c < NH) ? T_s[r][tid] : ((k == r) ? s_own : 0.f);
            float a0 = 0.f, a1 = 0.f, a2 = 0.f, a3 = 0.f;
            #pragma unroll
            for (int m = 0; m + 3 < r; m += 4) {
                a0 += U_s[(r * (r - 1)) / 2 + m    ] * w[m];
                a1 += U_s[(r * (r - 1)) / 2 + m + 1] * w[m + 1];
                a2 += U_s[(r * (r - 1)) / 2 + m + 2] * w[m + 2];
                a3 += U_s[(r * (r - 1)) / 2 + m + 3] * w[m + 3];
            }
            #pragma unroll
            for (int m = (r & ~3); m < r; ++m)
                a0 += U_s[(r * (r - 1)) / 2 + m] * w[m];
            w[r] = rhs + ((a0 + a1) + (a2 + a3));
        }
        #pragma unroll
        for (int r = 0; r < KK; ++r)
            W[(c >> 2) * 256 + r * 4 + (c & 3)] = w[r];
        return;
    }

    // ---- head copy: out[:,0:448] = eps + bias_sh (independent of everything)
    {
        const int hb = bid - (DD + 32);
        #pragma unroll
        for (int g = 0; g < 8; ++g) {
            const int b = hb * 8 + g;
            if (b < B) {
                #pragma unroll
                for (int j0 = 0; j0 < 2; ++j0) {
                    const int col = j0 * 256 + tid;
                    if (col < NH)
                        out[(size_t)b * NTOT + col] = eps[(size_t)b * NTOT + col] + bias_sh[col];
                }
            }
        }
    }
}

// ---------- Kernel B: z_tail = W_d @ eps, grouped by domain ----------
__global__ __launch_bounds__(512)
void fvae_main(const float* __restrict__ eps, const float* __restrict__ bias_ns,
               const float* __restrict__ ws, float* __restrict__ out)
{
    __shared__ float eps_s[MAXG][NTOT];
    __shared__ float part_s[8][MAXG][KK];
    __shared__ int   idx_s[MAXG];

    const int dom   = blockIdx.x & (DD - 1);
    const int slice = blockIdx.x >> 4;
    const int tid   = threadIdx.x;
    const int wave  = tid >> 6;
    const int lane  = tid & 63;

    const int*   counts = (const int*)ws;
    const int*   lists  = (const int*)((const char*)ws + WS_LISTS_OFF) + dom * LISTCAP;
    const float* __restrict__ W = (const float*)((const char*)ws + WS_W_OFF) + dom * (NTOT * KK);

    const int cnt     = counts[dom];
    const int G_total = (cnt > slice) ? (cnt - 1 - slice) / SLICES + 1 : 0;
    if (G_total == 0) return;

    for (int s0 = 0; s0 < G_total; s0 += MAXG) {
        const int Gc = min(MAXG, G_total - s0);
        if (tid < Gc) idx_s[tid] = lists[slice + (s0 + tid) * SLICES];
        __syncthreads();
        for (int v = tid; v < Gc * 128; v += 512) {          // stage eps rows, float4
            const int g = v >> 7, q = v & 127;
            *(float4*)&eps_s[g][q * 4] =
                *(const float4*)(eps + (size_t)idx_s[g] * NTOT + q * 4);
        }
        __syncthreads();

        // wave w covers j in [64w, 64w+64); lane = output row r
        float acc[MAXG];
        #pragma unroll
        for (int g = 0; g < MAXG; ++g) acc[g] = 0.f;
        #pragma unroll
        for (int qi = 0; qi < 16; ++qi) {
            const int q = wave * 16 + qi;
            const float4 Wq = *(const float4*)(W + q * 256 + lane * 4);  // coalesced
            #pragma unroll
            for (int g = 0; g < MAXG; ++g) {                  // static idx; g>=Gc discarded
                const float4 e = *(const float4*)&eps_s[g][q * 4];       // LDS broadcast
                acc[g] += Wq.x * e.x + Wq.y * e.y + Wq.z * e.z + Wq.w * e.w;
            }
        }
        #pragma unroll
        for (int g = 0; g < MAXG; ++g)
            part_s[wave][g][lane] = acc[g];
        __syncthreads();

        if (tid < MAXG * KK) {                                // cross-wave reduce + write
            const int g = tid >> 6, r = tid & 63;
            if (g < Gc) {
                float z = 0.f;
                #pragma unroll
                for (int wv = 0; wv < 8; ++wv) z += part_s[wv][g][r];
                out[(size_t)idx_s[g] * NTOT + NH + r] = z + bias_ns[dom * KK + r];
            }
        }
        __syncthreads();
    }
}

extern "C" void kernel_launch(void* const* d_in, const int* in_sizes, int n_in,
                              void* d_out, int out_size, void* d_ws, size_t ws_size,
                              hipStream_t stream) {
    const float* eps     = (const float*)d_in[0];
    const int*   dom     = (const int*)  d_in[1];
    const float* L_emb   = (const float*)d_in[2];
    const float* S_emb   = (const float*)d_in[3];
    const float* bias_ns = (const float*)d_in[4];
    const float* bias_sh = (const float*)d_in[5];
    float* out = (float*)d_out;
    float* ws  = (float*)d_ws;

    const int B = in_sizes[0] / NTOT;           // 1024
    const int headBlocks = (B + 7) / 8;         // 128
    fvae_prep<<<dim3(DD + 32 + headBlocks), dim3(256), 0, stream>>>(
        eps, dom, L_emb, S_emb, bias_sh, out, ws, B);
    fvae_main<<<dim3(DD * SLICES), dim3(512), 0, stream>>>(eps, bias_ns, ws, out);
}

// Round 4
// 32.936 us; speedup vs baseline: 6.5045x; 6.5045x over previous
//
#include <hip/hip_runtime.h>

// Problem constants (fixed by the reference)
#define NTOT 512   // N
#define NH   448   // N - K (identity head)
#define KK   64    // K (solved tail rows)
#define NL   30688 // strictly-lower entries in last K rows
#define DD   16    // domains
#define BB   1024  // batch
#define SLICES 16  // blocks per domain
#define MAXG 4     // samples per group iteration
#define SLCAP 64   // max samples per slice (worst case 1024/16)

// z = F_d eps, F_d = (I-L)^{-1} S  <=>  (I-L) z = S eps.
// Head rows: z_j = eps_j (+bias_sh). Tail: y_r = s_r*eps_{448+r} + T_r . eps[0:448],
// then z_tail = (I-U)^{-1} y (unit-lower 64x64 forward substitution).
// T row r at L_emb[dom] + 448r + r(r-1)/2; U[r][m] at +448+m.
// Block (dom, slice): wave0 ballot-ranks d[] (all 16 chunk loads PREFETCHED -> one
// latency) while waves 1-3 stage packed U; then groups of 4 same-domain samples
// share every T-row load (4 FMAs per load, eps hoisted to registers).
__global__ __launch_bounds__(256)
void fvae_fused(const float* __restrict__ eps,      // [B,512]
                const int*   __restrict__ dom_idx,  // [B]
                const float* __restrict__ L_emb,    // [16, NL]
                const float* __restrict__ S_emb,    // [16, 64]
                const float* __restrict__ bias_ns,  // [16, 64]
                const float* __restrict__ bias_sh,  // [448]
                float*       __restrict__ out)      // [B,512]
{
    const int dom   = blockIdx.x & (DD - 1);
    const int slice = blockIdx.x >> 4;
    const int tid   = threadIdx.x;
    const int wave  = tid >> 6;
    const int lane  = tid & 63;

    __shared__ int   list_s[SLCAP];
    __shared__ int   cnt_s;
    __shared__ float eps_s[MAXG][NTOT];
    __shared__ float y_s[MAXG][KK];
    __shared__ float U_s[(KK * (KK - 1)) / 2];   // packed strictly-lower 64x64

    const float* __restrict__ Ld = L_emb + (size_t)dom * NL;

    if (wave == 0) {
        // ---- scan: prefetch ALL chunk ids first (loads overlap -> one latency)
        int dm[BB / 64];
        #pragma unroll
        for (int t = 0; t < BB / 64; ++t) dm[t] = dom_idx[t * 64 + lane];
        int base = 0;
        #pragma unroll
        for (int t = 0; t < BB / 64; ++t) {
            const unsigned long long mt = __ballot(dm[t] == dom);
            if (dm[t] == dom) {
                const int rank = base + __popcll(mt & ((1ull << lane) - 1ull));
                if ((rank & (SLICES - 1)) == slice) list_s[rank >> 4] = t * 64 + lane;
            }
            base += __popcll(mt);
        }
        if (lane == 0)
            cnt_s = (base > slice) ? (base - 1 - slice) / SLICES + 1 : 0;
    } else if (dom != 0) {
        // ---- waves 1..3 stage packed U (r=0 row is empty; starts 1,2,3 cover all)
        for (int r = wave; r < KK; r += 3)
            if (lane < r)
                U_s[(r * (r - 1)) / 2 + lane] = Ld[r * NH + (r * (r - 1)) / 2 + NH + lane];
    }
    __syncthreads();

    const int G_total = cnt_s;
    if (G_total == 0) return;

    for (int s0 = 0; s0 < G_total; s0 += MAXG) {
        const int Gc = min(MAXG, G_total - s0);

        // ---- stage eps rows (float4, coalesced)
        for (int v = tid; v < Gc * (NTOT / 4); v += 256) {
            const int g = v >> 7, c = v & 127;
            *(float4*)&eps_s[g][c * 4] =
                *(const float4*)(eps + (size_t)list_s[s0 + g] * NTOT + c * 4);
        }
        __syncthreads();

        // ---- head: out[:,0:448] = eps + bias_sh (float4)
        for (int v = tid; v < Gc * (NH / 4); v += 256) {
            const int g = v / 112, c = v - g * 112;
            const float4 e  = *(const float4*)&eps_s[g][c * 4];
            const float4 bs = *(const float4*)(bias_sh + c * 4);
            float4 o; o.x = e.x + bs.x; o.y = e.y + bs.y; o.z = e.z + bs.z; o.w = e.w + bs.w;
            *(float4*)(out + (size_t)list_s[s0 + g] * NTOT + c * 4) = o;
        }

        if (dom != 0) {
            // ---- hoist eps into registers: ereg[g][k] = eps_s[g][lane+64k]
            float ereg[MAXG][7];
            #pragma unroll
            for (int g = 0; g < MAXG; ++g)
                #pragma unroll
                for (int k = 0; k < 7; ++k)
                    ereg[g][k] = eps_s[g][lane + 64 * k];

            // ---- phase 2: 16 rows per wave; each T-row load feeds 4 samples
            #pragma unroll 4
            for (int r = wave; r < KK; r += 4) {
                const float* __restrict__ Tr = Ld + r * NH + (r * (r - 1)) / 2;
                const float t0 = Tr[lane],       t1 = Tr[lane + 64],
                            t2 = Tr[lane + 128], t3 = Tr[lane + 192],
                            t4 = Tr[lane + 256], t5 = Tr[lane + 320],
                            t6 = Tr[lane + 384];
                float a0 = t0*ereg[0][0] + t1*ereg[0][1] + t2*ereg[0][2] + t3*ereg[0][3]
                         + t4*ereg[0][4] + t5*ereg[0][5] + t6*ereg[0][6];
                float a1 = t0*ereg[1][0] + t1*ereg[1][1] + t2*ereg[1][2] + t3*ereg[1][3]
                         + t4*ereg[1][4] + t5*ereg[1][5] + t6*ereg[1][6];
                float a2 = t0*ereg[2][0] + t1*ereg[2][1] + t2*ereg[2][2] + t3*ereg[2][3]
                         + t4*ereg[2][4] + t5*ereg[2][5] + t6*ereg[2][6];
                float a3 = t0*ereg[3][0] + t1*ereg[3][1] + t2*ereg[3][2] + t3*ereg[3][3]
                         + t4*ereg[3][4] + t5*ereg[3][5] + t6*ereg[3][6];
                // butterfly-merged reduce: 10 shfls, sum of a_g lands at lane g
                a0 += __shfl_xor(a0, 1);  a1 += __shfl_xor(a1, 1);
                a2 += __shfl_xor(a2, 1);  a3 += __shfl_xor(a3, 1);
                float c0 = (lane & 1) ? a1 : a0;
                float c1 = (lane & 1) ? a3 : a2;
                c0 += __shfl_xor(c0, 2);  c1 += __shfl_xor(c1, 2);
                float dsum = (lane & 2) ? c1 : c0;
                dsum += __shfl_xor(dsum, 4);
                dsum += __shfl_xor(dsum, 8);
                dsum += __shfl_xor(dsum, 16);
                dsum += __shfl_xor(dsum, 32);
                if (lane < MAXG) {
                    const float sr = S_emb[dom * KK + r];
                    y_s[lane][r] = dsum + sr * eps_s[lane][NH + r];
                }
            }
            __syncthreads();

            // ---- phase 3: wave g solves sample g (lane = row), r1-proven chain
            if (wave < Gc) {
                const int m  = lane;
                const int tb = (m * (m - 1)) / 2;
                float t[KK - 1];
                #pragma unroll
                for (int r = 0; r < KK - 1; ++r)
                    t[r] = (r < m) ? U_s[tb + r] : 0.f;
                float z = y_s[wave][m];
                #pragma unroll
                for (int r = 0; r < KK - 1; ++r)
                    z += t[r] * __shfl(z, r);   // lane r's z final by step r
                out[(size_t)list_s[s0 + wave] * NTOT + NH + m] = z + bias_ns[dom * KK + m];
            }
        } else {
            // ---- domain 0: L=0, S=I -> z_tail = eps_tail
            for (int v = tid; v < Gc * KK; v += 256) {
                const int g = v >> 6, m = v & 63;
                out[(size_t)list_s[s0 + g] * NTOT + NH + m] = eps_s[g][NH + m] + bias_ns[m];
            }
        }
        __syncthreads();   // protect eps_s/y_s before next group
    }
}

extern "C" void kernel_launch(void* const* d_in, const int* in_sizes, int n_in,
                              void* d_out, int out_size, void* d_ws, size_t ws_size,
                              hipStream_t stream) {
    const float* eps     = (const float*)d_in[0];
    const int*   dom     = (const int*)  d_in[1];
    const float* L_emb   = (const float*)d_in[2];
    const float* S_emb   = (const float*)d_in[3];
    const float* bias_ns = (const float*)d_in[4];
    const float* bias_sh = (const float*)d_in[5];
    float* out = (float*)d_out;

    fvae_fused<<<dim3(DD * SLICES), dim3(256), 0, stream>>>(
        eps, dom, L_emb, S_emb, bias_ns, bias_sh, out);
}

// Round 5
// 26.457 us; speedup vs baseline: 8.0975x; 1.2449x over previous
//
#include <hip/hip_runtime.h>

// Problem constants (fixed by the reference)
#define NTOT 512   // N
#define NH   448   // N - K (identity head)
#define KK   64    // K (solved tail rows)
#define NL   30688 // strictly-lower entries in last K rows
#define DD   16    // domains

// z_tail = W_d @ eps, with W_d = (I-U_d)^{-1} [T_d | diag(s_d)]  (64 x 512).
// Row i=448+m of L_emb[dom] packs: T[m][0:448] at m*448+m(m-1)/2, then U[m][0:m].
// W stored quad-packed transposed: Wq[dom][(c>>2)*256 + r*4 + (c&3)]
// so kernel B reads contiguous 1 KB float4 per wave.

// ---------- Kernel A: build W, one wave per column (8192 waves, no LDS) ----------
__global__ __launch_bounds__(256)
void fvae_buildW(const float* __restrict__ L_emb,   // [16, NL]
                 const float* __restrict__ S_emb,   // [16, 64]
                 float*       __restrict__ Wq)      // [16, 512*64] ws
{
    const int dom = blockIdx.x >> 7;          // 16 doms x 128 colgroups
    const int cg  = blockIdx.x & 127;
    const int w   = threadIdx.x >> 6;
    const int m   = threadIdx.x & 63;         // lane = row
    const int c   = cg * 4 + w;               // column 0..511 (wave-uniform)

    float* __restrict__ Wd = Wq + (size_t)dom * (NTOT * KK);

    if (dom == 0) {                           // L=0, S=I -> W = [0 | I]
        Wd[(c >> 2) * 256 + m * 4 + (c & 3)] = (c - NH == m) ? 1.f : 0.f;
        return;
    }

    const float* __restrict__ Ld = L_emb + (size_t)dom * NL;
    const int mb = m * NH + (m * (m - 1)) / 2;

    // rhs: T[m][c] for c<448, else s_m on the diagonal
    float rhs;
    if (c < NH) {                             // wave-uniform branch
        rhs = Ld[mb + c];
    } else {
        const float sm = S_emb[dom * KK + m];
        rhs = (c - NH == m) ? sm : 0.f;
    }

    // U row m: unconditional in-bounds loads (r>=m reads next row's data), masked to 0
    float t[KK - 1];
    #pragma unroll
    for (int r = 0; r < KK - 1; ++r) {
        const float v = Ld[mb + NH + r];      // max idx: mb(63)+448+62 = NL-1
        t[r] = (r < m) ? v : 0.f;
    }

    // forward substitution: lane r's z is final by step r (r1-proven pattern)
    float z = rhs;
    #pragma unroll
    for (int r = 0; r < KK - 1; ++r)
        z += t[r] * __shfl(z, r);

    Wd[(c >> 2) * 256 + m * 4 + (c & 3)] = z;
}

// ---------- Kernel B: per-sample matvec + head copy (no chains, no scan) ----------
__global__ __launch_bounds__(256)
void fvae_apply(const float* __restrict__ eps,      // [B,512]
                const int*   __restrict__ dom_idx,  // [B]
                const float* __restrict__ Wq,       // [16, 512*64]
                const float* __restrict__ bias_ns,  // [16, 64]
                const float* __restrict__ bias_sh,  // [448]
                float*       __restrict__ out)      // [B,512]
{
    const int b   = blockIdx.x;
    const int tid = threadIdx.x;
    const int w   = tid >> 6;
    const int l   = tid & 63;

    __shared__ float eps_s[NTOT];
    __shared__ float part_s[4][KK];

    const int dom = dom_idx[b];
    const float* __restrict__ eb = eps + (size_t)b * NTOT;
    float*       __restrict__ ob = out + (size_t)b * NTOT;

    // stage eps (float2 per thread, coalesced)
    const float2 e2 = *(const float2*)(eb + tid * 2);
    *(float2*)&eps_s[tid * 2] = e2;

    // head: out[:,0:448] = eps + bias_sh (reuses staged register value)
    if (tid < NH / 2) {
        const float2 bs = *(const float2*)(bias_sh + tid * 2);
        float2 o; o.x = e2.x + bs.x; o.y = e2.y + bs.y;
        *(float2*)(ob + tid * 2) = o;
    }
    __syncthreads();

    // matvec: lane l = output row; wave w covers q = 4i+w (32 independent float4 loads)
    const float* __restrict__ Wd = Wq + (size_t)dom * (NTOT * KK);
    float acc = 0.f;
    #pragma unroll
    for (int i = 0; i < 32; ++i) {
        const int q = i * 4 + w;
        const float4 Wv = *(const float4*)(Wd + q * 256 + l * 4);  // 1KB/wave, coalesced
        const float4 ev = *(const float4*)&eps_s[q * 4];           // uniform -> broadcast
        acc += Wv.x * ev.x + Wv.y * ev.y + Wv.z * ev.z + Wv.w * ev.w;
    }
    part_s[w][l] = acc;
    __syncthreads();

    if (tid < KK) {
        const float z = part_s[0][tid] + part_s[1][tid]
                      + part_s[2][tid] + part_s[3][tid];
        ob[NH + tid] = z + bias_ns[dom * KK + tid];
    }
}

extern "C" void kernel_launch(void* const* d_in, const int* in_sizes, int n_in,
                              void* d_out, int out_size, void* d_ws, size_t ws_size,
                              hipStream_t stream) {
    const float* eps     = (const float*)d_in[0];
    const int*   dom     = (const int*)  d_in[1];
    const float* L_emb   = (const float*)d_in[2];
    const float* S_emb   = (const float*)d_in[3];
    const float* bias_ns = (const float*)d_in[4];
    const float* bias_sh = (const float*)d_in[5];
    float* out = (float*)d_out;
    float* Wq  = (float*)d_ws;   // 16*512*64*4 = 2 MB

    const int B = in_sizes[0] / NTOT;   // 1024
    fvae_buildW<<<dim3(DD * 128), dim3(256), 0, stream>>>(L_emb, S_emb, Wq);
    fvae_apply <<<dim3(B),        dim3(256), 0, stream>>>(eps, dom, Wq, bias_ns,
                                                          bias_sh, out);
}